// Round 7
// baseline (173.709 us; speedup 1.0000x reference)
//
#include <hip/hip_runtime.h>
#include <hip/hip_bf16.h>

// Problem constants
#define BB   4
#define SS   2048
#define DM   256
#define HH   4
#define DHH  64
#define KSPL 4        // k-split factor (additive softmax partials)
#define KLEN (SS / KSPL)   // 512 k per block

typedef unsigned short ushort_t;
typedef unsigned int   uint_t;
using short8   = __attribute__((ext_vector_type(8))) short;
using ushort8  = __attribute__((ext_vector_type(8))) unsigned short;
using ushort4v = __attribute__((ext_vector_type(4))) unsigned short;
using float4v  = __attribute__((ext_vector_type(4))) float;

__device__ __forceinline__ ushort_t f2bf(float f) {
  uint_t u = __float_as_uint(f);
  uint_t r = (u + 0x7FFFu + ((u >> 16) & 1u)) >> 16;  // RNE
  return (ushort_t)r;
}

// ---------------------------------------------------------------------------
// Kernel 0: fused prep.
// Blocks 0..47: coalesced LDS-tiled transposes Wk/Wv/Wo -> bf16 WT[o][c].
// Blocks 48..303 (o = bi-48 = h*64+e):
//   M'col[d] = (d==e)/8 + (alpha/512)*sum_{a,r} W2[h,d,a,r]*W2[h,a,e,r]
//   WcT[o][c] = sum_d Wq[c][h*64+d] * M'col[d]   (rank-2 interaction folded
//   into the Q projection; scores collapse from 320 to 64 dims)
//   bc[o]     = sum_d bq[h*64+d]   * M'col[d]
// ---------------------------------------------------------------------------
__global__ __launch_bounds__(256) void k_pre(
    const float* __restrict__ Wk, const float* __restrict__ Wv,
    const float* __restrict__ Wo, const float* __restrict__ Wq,
    const float* __restrict__ bq, const float* __restrict__ W2,
    const float* __restrict__ alpha_p,
    ushort_t* __restrict__ WkT, ushort_t* __restrict__ WvT,
    ushort_t* __restrict__ WoT, ushort_t* __restrict__ WcT,
    float* __restrict__ bc) {
  __shared__ float sT[64 * 65];
  __shared__ __align__(16) float sM[64];
  const int t = threadIdx.x;
  const int bi = blockIdx.x;
  if (bi < 48) {
    int m = bi >> 4, tile = bi & 15;
    int ot = tile >> 2, ct = tile & 3;
    const float* src = (m == 0) ? Wk : (m == 1) ? Wv : Wo;
    ushort_t* dst = (m == 0) ? WkT : (m == 1) ? WvT : WoT;
#pragma unroll
    for (int it = 0; it < 16; ++it) {
      int i = it * 4 + (t >> 6), j = t & 63;
      sT[i * 65 + j] = src[(ct * 64 + i) * 256 + ot * 64 + j];
    }
    __syncthreads();
#pragma unroll
    for (int it = 0; it < 16; ++it) {
      int jj = it * 4 + (t >> 6), ii = t & 63;
      dst[(ot * 64 + jj) * 256 + ct * 64 + ii] = f2bf(sT[ii * 65 + jj]);
    }
  } else {
    int o = bi - 48;          // h*64 + e
    int h = o >> 6, e = o & 63;
    if (t < 64) {
      const float* Wd = W2 + h * 16384 + t * 256;
      const float* We = W2 + h * 16384 + e * 4;
      float s = 0.f;
#pragma unroll 8
      for (int a = 0; a < 64; ++a) {
        float4 x = *(const float4*)(Wd + a * 4);
        float4 y = *(const float4*)(We + a * 256);
        s += x.x * y.x + x.y * y.y + x.z * y.z + x.w * y.w;
      }
      sM[t] = (t == e ? 0.125f : 0.f) + alpha_p[0] * (1.f / 512.f) * s;
    }
    __syncthreads();
    const float* Wrow = Wq + t * 256 + h * 64;
    float s = 0.f;
#pragma unroll
    for (int d4 = 0; d4 < 16; ++d4) {
      float4 x = *(const float4*)(Wrow + d4 * 4);
      float4 mm = *(const float4*)(sM + d4 * 4);
      s += x.x * mm.x + x.y * mm.y + x.z * mm.z + x.w * mm.w;
    }
    WcT[o * 256 + t] = f2bf(s);
    if (t == 0) {
      float sb = 0.f;
      for (int d = 0; d < 64; ++d) sb += bq[h * 64 + d] * sM[d];
      bc[o] = sb;
    }
  }
}

// ---------------------------------------------------------------------------
// Kernel 1: tiled MFMA projection. Grid (128 row-tiles, 3 matrices), 256 thr
// (4 waves). Each block: 64 rows x 256 cols, K=256. A staged once in LDS
// (32 KB); per wave 128 MFMAs with B-fragments straight from L2-hot WT.
// Epilogue round-trips C through LDS so ALL global stores are coalesced
// 16 B: Q/K row-major [bh][s][64]; V transposed [bh][d][s] (8 threads cover
// one d-row's 64 s -> 128 B contiguous).
// ---------------------------------------------------------------------------
__global__ __launch_bounds__(256) void k_proj(
    const float* __restrict__ q_in, const float* __restrict__ k_in,
    const float* __restrict__ v_in,
    const ushort_t* __restrict__ WcT, const ushort_t* __restrict__ WkT,
    const ushort_t* __restrict__ WvT,
    const float* __restrict__ bc, const float* __restrict__ bk,
    const float* __restrict__ bv,
    ushort_t* __restrict__ Qa, ushort_t* __restrict__ Ka,
    ushort_t* __restrict__ VTg) {
  __shared__ ushort_t sX[64 * 256];   // 32 KB; staging, then C round-trip
  const int t = threadIdx.x;
  const int w = t >> 6, lane = t & 63, g = lane >> 4, l16 = lane & 15;
  const int m = blockIdx.y;
  const int row0 = blockIdx.x * 64;
  const int b = row0 >> 11, s0 = row0 & (SS - 1);
  const float* src = (m == 0) ? q_in : (m == 1) ? k_in : v_in;
  const ushort_t* WT = (m == 0) ? WcT : (m == 1) ? WkT : WvT;
  const float* bias = (m == 0) ? bc : (m == 1) ? bk : bv;

  // ---- stage X: 64 rows fp32 -> bf16 swizzled ----
#pragma unroll
  for (int it = 0; it < 8; ++it) {
    int blk = it * 256 + t;           // 2048 16B-blocks
    int r = blk >> 5, c16 = blk & 31;
    const float* p = src + (size_t)(row0 + r) * DM + c16 * 8;
    float4 a0 = *(const float4*)p, a1 = *(const float4*)(p + 4);
    ushort8 u;
    u[0] = f2bf(a0.x); u[1] = f2bf(a0.y); u[2] = f2bf(a0.z); u[3] = f2bf(a0.w);
    u[4] = f2bf(a1.x); u[5] = f2bf(a1.y); u[6] = f2bf(a1.z); u[7] = f2bf(a1.w);
    *(ushort8*)&sX[r * 256 + ((c16 ^ (r & 7)) << 3)] = u;
  }
  __syncthreads();

  // ---- A-fragments: wave w owns rows w*16 .. +15 ----
  short8 af[8];
  {
    int r = w * 16 + l16;
#pragma unroll
    for (int kc = 0; kc < 8; ++kc)
      af[kc] = *(const short8*)&sX[r * 256 + (((kc * 4 + g) ^ (r & 7)) << 3)];
  }

  // ---- GEMM: 16 col-tiles x 8 k-chunks ----
  float4v acc[16];
#pragma unroll
  for (int ct = 0; ct < 16; ++ct) acc[ct] = (float4v){0.f, 0.f, 0.f, 0.f};
#pragma unroll
  for (int ct = 0; ct < 16; ++ct) {
#pragma unroll
    for (int kc = 0; kc < 8; ++kc) {
      short8 bf = *(const short8*)&WT[(ct * 16 + l16) * 256 + kc * 32 + g * 8];
      acc[ct] = __builtin_amdgcn_mfma_f32_16x16x32_bf16(af[kc], bf, acc[ct],
                                                        0, 0, 0);
    }
  }
  __syncthreads();   // all af reads done before sX is overwritten

  // ---- C -> LDS (bf16, bias added), swizzled [row][col] ----
#pragma unroll
  for (int ct = 0; ct < 16; ++ct) {
    int col = ct * 16 + l16;
    float bv = bias[col];
#pragma unroll
    for (int r4 = 0; r4 < 4; ++r4) {
      int row = w * 16 + g * 4 + r4;
      sX[row * 256 + (((col >> 3) ^ (row & 7)) << 3) + (col & 7)] =
          f2bf(acc[ct][r4] + bv);
    }
  }
  __syncthreads();

  // ---- coalesced global stores ----
  if (m < 2) {
    ushort_t* dst = (m == 0) ? Qa : Ka;
#pragma unroll
    for (int it = 0; it < 8; ++it) {
      int blk = it * 256 + t;
      int r = blk >> 5, c16 = blk & 31;
      ushort8 u = *(const ushort8*)&sX[r * 256 + ((c16 ^ (r & 7)) << 3)];
      int h = c16 >> 3, dh = (c16 * 8) & 63;
      *(ushort8*)&dst[((size_t)(b * HH + h) * SS + s0 + r) * DHH + dh] = u;
    }
  } else {
#pragma unroll
    for (int it = 0; it < 8; ++it) {
      int idx = it * 256 + t;         // 256 cols x 8 s-blocks
      int col = idx >> 3, sblk = idx & 7;
      ushort8 u;
#pragma unroll
      for (int ji = 0; ji < 8; ++ji) {
        int row = sblk * 8 + ji;
        u[ji] = sX[row * 256 + (((col >> 3) ^ (row & 7)) << 3) + (col & 7)];
      }
      int h = col >> 6, dh = col & 63;
      *(ushort8*)&VTg[((size_t)(b * HH + h) * DHH + dh) * SS + s0 + sblk * 8] = u;
    }
  }
}

// ---------------------------------------------------------------------------
// Kernel 2: flash attention, 64-dim scores, TQ=128, k-split x4. (unchanged)
// ---------------------------------------------------------------------------
__global__ __launch_bounds__(256, 4) void k_attn(
    const ushort_t* __restrict__ Qa, const ushort_t* __restrict__ Ka,
    const ushort_t* __restrict__ VTg,
    float* __restrict__ Opart, float* __restrict__ lpart) {
  __shared__ ushort_t sKa[64 * 64];     //  8 KB
  __shared__ ushort_t sVT[64 * 64];     //  8 KB
  __shared__ ushort_t sPT[128 * 64];    // 16 KB

  const int t = threadIdx.x;
  const int w = t >> 6, lane = t & 63, g = lane >> 4, l16 = lane & 15;
  const int bh = blockIdx.y;
  const int q0 = blockIdx.x * 128;
  const int ks = blockIdx.z;

  short8 qfrag[2][2];
#pragma unroll
  for (int s = 0; s < 2; ++s) {
    const ushort_t* qp =
        Qa + ((size_t)bh * SS + q0 + s * 64 + w * 16 + l16) * DHH + g * 8;
    qfrag[s][0] = *(const short8*)(qp);
    qfrag[s][1] = *(const short8*)(qp + 32);
  }

  const ushort_t* KaB = Ka + (size_t)bh * SS * DHH + (size_t)ks * KLEN * DHH;
  const ushort_t* VTB = VTg + (size_t)bh * DHH * SS + ks * KLEN;

  const int r0 = t >> 3, c0 = t & 7, r1 = r0 + 32;
  const int sw0 = r0 * 64 + ((c0 ^ (r0 & 7)) << 3);
  const int sw1 = r1 * 64 + ((c0 ^ (r1 & 7)) << 3);

  float l_run[2] = {0.f, 0.f};
  float4v oacc[2][4];
#pragma unroll
  for (int s = 0; s < 2; ++s)
#pragma unroll
    for (int dj = 0; dj < 4; ++dj) oacc[s][dj] = (float4v){0.f, 0.f, 0.f, 0.f};

  for (int kch = 0; kch < KLEN / 64; ++kch) {
    __syncthreads();
    {
      short8 k0 = *(const short8*)(KaB + (size_t)(kch * 64 + r0) * DHH + c0 * 8);
      short8 k1 = *(const short8*)(KaB + (size_t)(kch * 64 + r1) * DHH + c0 * 8);
      short8 v0 = *(const short8*)(VTB + (size_t)r0 * SS + kch * 64 + c0 * 8);
      short8 v1 = *(const short8*)(VTB + (size_t)r1 * SS + kch * 64 + c0 * 8);
      *(short8*)(sKa + sw0) = k0;
      *(short8*)(sKa + sw1) = k1;
      *(short8*)(sVT + sw0) = v0;
      *(short8*)(sVT + sw1) = v1;
    }
    __syncthreads();

    float4v sacc[2][4];
#pragma unroll
    for (int s = 0; s < 2; ++s)
#pragma unroll
      for (int kj = 0; kj < 4; ++kj)
        sacc[s][kj] = (float4v){-20.f, -20.f, -20.f, -20.f};
#pragma unroll
    for (int kc = 0; kc < 2; ++kc) {
#pragma unroll
      for (int kj = 0; kj < 4; ++kj) {
        int krow = kj * 16 + l16;
        short8 kf = *(const short8*)(sKa + krow * 64 +
                                     (((kc * 4 + g) ^ (krow & 7)) << 3));
        sacc[0][kj] = __builtin_amdgcn_mfma_f32_16x16x32_bf16(
            kf, qfrag[0][kc], sacc[0][kj], 0, 0, 0);
        sacc[1][kj] = __builtin_amdgcn_mfma_f32_16x16x32_bf16(
            kf, qfrag[1][kc], sacc[1][kj], 0, 0, 0);
      }
    }

#pragma unroll
    for (int s = 0; s < 2; ++s) {
      int qrow = s * 64 + w * 16 + l16;
      float lp = 0.f;
#pragma unroll
      for (int kj = 0; kj < 4; ++kj) {
        float p0 = __expf(sacc[s][kj][0]);
        float p1 = __expf(sacc[s][kj][1]);
        float p2 = __expf(sacc[s][kj][2]);
        float p3 = __expf(sacc[s][kj][3]);
        uint_t u01 = __builtin_amdgcn_perm(__float_as_uint(p1),
                                           __float_as_uint(p0), 0x07060302u);
        uint_t u23 = __builtin_amdgcn_perm(__float_as_uint(p3),
                                           __float_as_uint(p2), 0x07060302u);
        lp += __uint_as_float(__float_as_uint(p0) & 0xFFFF0000u);
        lp += __uint_as_float(__float_as_uint(p1) & 0xFFFF0000u);
        lp += __uint_as_float(__float_as_uint(p2) & 0xFFFF0000u);
        lp += __uint_as_float(__float_as_uint(p3) & 0xFFFF0000u);
        int kbase = kj * 16 + g * 4;
        uint2 pack; pack.x = u01; pack.y = u23;
        *(uint2*)(sPT + qrow * 64 + (((kbase >> 3) ^ (qrow & 7)) << 3) +
                  (kbase & 7)) = pack;
      }
      l_run[s] += lp;
    }

#pragma unroll
    for (int ck = 0; ck < 2; ++ck) {
      short8 vb[4];
#pragma unroll
      for (int dj = 0; dj < 4; ++dj) {
        int vrow = dj * 16 + l16;
        vb[dj] = *(const short8*)(sVT + vrow * 64 +
                                  (((ck * 4 + g) ^ (vrow & 7)) << 3));
      }
#pragma unroll
      for (int s = 0; s < 2; ++s) {
        int qrow = s * 64 + w * 16 + l16;
        short8 pa = *(const short8*)(sPT + qrow * 64 +
                                     (((ck * 4 + g) ^ (qrow & 7)) << 3));
#pragma unroll
        for (int dj = 0; dj < 4; ++dj)
          oacc[s][dj] = __builtin_amdgcn_mfma_f32_16x16x32_bf16(
              pa, vb[dj], oacc[s][dj], 0, 0, 0);
      }
    }
  }

  const int b = bh >> 2, h = bh & 3;
  float* Ob = Opart + (size_t)ks * (8192 * 256);
#pragma unroll
  for (int s = 0; s < 2; ++s) {
    l_run[s] += __shfl_xor(l_run[s], 16, 64);
    l_run[s] += __shfl_xor(l_run[s], 32, 64);
    if (g == 0)
      lpart[(size_t)ks * (8192 * 4) +
            ((size_t)b * SS + q0 + s * 64 + w * 16 + l16) * 4 + h] = l_run[s];
#pragma unroll
    for (int r = 0; r < 4; ++r) {
      size_t row = (size_t)b * SS + q0 + s * 64 + w * 16 + g * 4 + r;
#pragma unroll
      for (int dj = 0; dj < 4; ++dj)
        Ob[row * DM + h * DHH + dj * 16 + l16] = oacc[s][dj][r];
    }
  }
}

// ---------------------------------------------------------------------------
// Kernel 3: combine KSPL partials, normalize, then Out = A @ Wo + bo.
// ---------------------------------------------------------------------------
__global__ __launch_bounds__(512) void k_out(
    const float* __restrict__ Opart, const float* __restrict__ lpart,
    const ushort_t* __restrict__ WoT, const float* __restrict__ bo,
    float* __restrict__ Out) {
  __shared__ ushort_t sA[16 * 256];
  const int t = threadIdx.x;
  const int w = t >> 6, lane = t & 63, g = lane >> 4, l16 = lane & 15;
  const int row0 = blockIdx.x * 16;
  {
    int r = t >> 5, cf = (t & 31) * 8;
    size_t row = row0 + r;
    int h = cf >> 6;
    float l = 0.f;
    float s0 = 0.f, s1 = 0.f, s2 = 0.f, s3 = 0.f,
          s4 = 0.f, s5 = 0.f, s6 = 0.f, s7 = 0.f;
#pragma unroll
    for (int ks = 0; ks < KSPL; ++ks) {
      l += lpart[(size_t)ks * (8192 * 4) + row * 4 + h];
      const float* o = Opart + (size_t)ks * (8192 * 256) + row * DM + cf;
      float4 a0 = *(const float4*)o, a1 = *(const float4*)(o + 4);
      s0 += a0.x; s1 += a0.y; s2 += a0.z; s3 += a0.w;
      s4 += a1.x; s5 += a1.y; s6 += a1.z; s7 += a1.w;
    }
    float linv = 1.0f / l;
    ushort8 u;
    u[0] = f2bf(s0 * linv); u[1] = f2bf(s1 * linv);
    u[2] = f2bf(s2 * linv); u[3] = f2bf(s3 * linv);
    u[4] = f2bf(s4 * linv); u[5] = f2bf(s5 * linv);
    u[6] = f2bf(s6 * linv); u[7] = f2bf(s7 * linv);
    *(ushort8*)&sA[r * 256 + (((cf >> 3) ^ (r & 7)) << 3)] = u;
  }
  __syncthreads();

  float4v acc[2];
  acc[0] = (float4v){0.f, 0.f, 0.f, 0.f};
  acc[1] = (float4v){0.f, 0.f, 0.f, 0.f};
#pragma unroll
  for (int kc = 0; kc < 8; ++kc) {
    short8 af = *(const short8*)&sA[l16 * 256 + (((kc * 4 + g) ^ (l16 & 7)) << 3)];
#pragma unroll
    for (int ct = 0; ct < 2; ++ct) {
      int col = w * 32 + ct * 16 + l16;
      short8 bf = *(const short8*)&WoT[col * 256 + kc * 32 + g * 8];
      acc[ct] = __builtin_amdgcn_mfma_f32_16x16x32_bf16(af, bf, acc[ct], 0, 0, 0);
    }
  }
#pragma unroll
  for (int ct = 0; ct < 2; ++ct) {
    int col = w * 32 + ct * 16 + l16;
    float bv = bo[col];
#pragma unroll
    for (int r = 0; r < 4; ++r)
      Out[(size_t)(row0 + g * 4 + r) * DM + col] = acc[ct][r] + bv;
  }
}

// ---------------------------------------------------------------------------
extern "C" void kernel_launch(void* const* d_in, const int* in_sizes, int n_in,
                              void* d_out, int out_size, void* d_ws, size_t ws_size,
                              hipStream_t stream) {
  (void)in_sizes; (void)n_in; (void)out_size; (void)ws_size;
  const float* q_in  = (const float*)d_in[0];
  const float* k_in  = (const float*)d_in[1];
  const float* v_in  = (const float*)d_in[2];
  const float* Wq    = (const float*)d_in[3];
  const float* bq    = (const float*)d_in[4];
  const float* Wk    = (const float*)d_in[5];
  const float* bk    = (const float*)d_in[6];
  const float* Wv    = (const float*)d_in[7];
  const float* bv    = (const float*)d_in[8];
  const float* W2    = (const float*)d_in[9];
  const float* alpha = (const float*)d_in[10];
  const float* Wo    = (const float*)d_in[11];
  const float* bo    = (const float*)d_in[12];
  float* out = (float*)d_out;

  // workspace layout (bytes):
  // Qa 4,194,304 | Ka 4,194,304 | VTg 4,194,304 | Opart 4x8,388,608 |
  // lpart 2,097,152 | WkT/WvT/WoT/WcT 4x131,072 | bc 1,024  => ~49 MB
  char* ws = (char*)d_ws;
  ushort_t* Qa    = (ushort_t*)ws;
  ushort_t* Ka    = (ushort_t*)(ws + 4194304);
  ushort_t* VTg   = (ushort_t*)(ws + 8388608);
  float*    Opart = (float*)(ws + 12582912);
  float*    lpart = (float*)(ws + 46137344);
  ushort_t* WkT   = (ushort_t*)(ws + 48234496);
  ushort_t* WvT   = (ushort_t*)(ws + 48365568);
  ushort_t* WoT   = (ushort_t*)(ws + 48496640);
  ushort_t* WcT   = (ushort_t*)(ws + 48627712);
  float*    bc    = (float*)(ws + 48758784);

  hipLaunchKernelGGL(k_pre, dim3(304), dim3(256), 0, stream,
                     Wk, Wv, Wo, Wq, bq, W2, alpha, WkT, WvT, WoT, WcT, bc);
  hipLaunchKernelGGL(k_proj, dim3(128, 3), dim3(256), 0, stream,
                     q_in, k_in, v_in, WcT, WkT, WvT, bc, bk, bv, Qa, Ka, VTg);
  hipLaunchKernelGGL(k_attn, dim3(SS / 128, BB * HH, KSPL), dim3(256), 0,
                     stream, Qa, Ka, VTg, Opart, lpart);
  hipLaunchKernelGGL(k_out, dim3(512), dim3(512), 0, stream,
                     Opart, lpart, WoT, bo, out);
}